// Round 5
// baseline (831.458 us; speedup 1.0000x reference)
//
#include <hip/hip_runtime.h>
#include <stdint.h>

#define INS 768
#define OUTS 64
#define BB 8
#define SS 2048
#define GRID 1024
#define MAGIC 0x5AD0F00Du
#define LDP 40

typedef __attribute__((ext_vector_type(8))) short short8;
typedef __attribute__((ext_vector_type(4))) float f32x4;

__device__ inline unsigned short f2bf(float f) {
  union { float f; uint32_t u; } v; v.f = f;
  uint32_t r = v.u + 0x7FFFu + ((v.u >> 16) & 1u);  // RNE
  return (unsigned short)(r >> 16);
}

__device__ inline short8 cvt8(float4 a, float4 b) {
  short8 r;
  r[0] = (short)f2bf(a.x); r[1] = (short)f2bf(a.y);
  r[2] = (short)f2bf(a.z); r[3] = (short)f2bf(a.w);
  r[4] = (short)f2bf(b.x); r[5] = (short)f2bf(b.y);
  r[6] = (short)f2bf(b.z); r[7] = (short)f2bf(b.w);
  return r;
}

// Grid barrier via ws flags. ws is re-poisoned 0xAA before every launch, so
// cells start != MAGIC. Block 0 aggregates, flags[0] doubles as the done cell.
__device__ inline void gbar(uint32_t* flags, int blk, int tid) {
  __threadfence();
  __syncthreads();
  if (blk == 0) {
    for (int i = 1 + tid; i < GRID; i += 256)
      while (__hip_atomic_load(&flags[i], __ATOMIC_ACQUIRE, __HIP_MEMORY_SCOPE_AGENT) != MAGIC)
        __builtin_amdgcn_s_sleep(2);
    __syncthreads();
    if (tid == 0)
      __hip_atomic_store(&flags[0], MAGIC, __ATOMIC_RELEASE, __HIP_MEMORY_SCOPE_AGENT);
  } else {
    if (tid == 0) {
      __hip_atomic_store(&flags[blk], MAGIC, __ATOMIC_RELEASE, __HIP_MEMORY_SCOPE_AGENT);
      while (__hip_atomic_load(&flags[0], __ATOMIC_ACQUIRE, __HIP_MEMORY_SCOPE_AGENT) != MAGIC)
        __builtin_amdgcn_s_sleep(2);
    }
    __syncthreads();
  }
  __threadfence();
}

struct QkvF { float4 x0, x1; short8 b[3]; };
struct AttF { short8 k[2][2]; short8 v[4]; };

// Single fused kernel: phase0 weight cast -> gbar -> phase1 QKV -> gbar ->
// phase2 attention (key-split across the 4 waves, combined in LDS).
// __launch_bounds__(256,4): VGPR<=128, LDS 21.8KB -> guaranteed 4 blocks/CU,
// all 1024 blocks co-resident (deadlock-free spin barriers).
__global__ __launch_bounds__(256, 4) void fused(
    const float* __restrict__ X,
    const float* __restrict__ Wq, const float* __restrict__ bq,
    const float* __restrict__ Wk, const float* __restrict__ bk,
    const float* __restrict__ Wv, const float* __restrict__ bv,
    unsigned short* __restrict__ Wt, float* __restrict__ bc,
    unsigned short* __restrict__ Qg, unsigned short* __restrict__ Kg,
    unsigned short* __restrict__ Vtg,
    uint32_t* __restrict__ flags0, uint32_t* __restrict__ flags1,
    float* __restrict__ out) {
  __shared__ __align__(16) char smem[21760];  // [0,16640): Ls | Obuf+Lbuf ; [16640,21760): Ps
  const int tid  = threadIdx.x;
  const int blk  = blockIdx.x;
  const int wave = tid >> 6, lane = tid & 63;
  const int quad = lane >> 4, l16 = lane & 15;

  // ---------------- phase 0: weight cast+transpose (blocks 0..35) ------------
  if (blk < 36) {
    float (*Ls)[65] = reinterpret_cast<float(*)[65]>(smem);
    const int mat = blk / 12, kt = blk % 12;
    const float* W; const float* bs; float scale;
    if (mat == 0)      { W = Wq; bs = bq; scale = 0.125f; }
    else if (mat == 1) { W = Wk; bs = bk; scale = 1.0f; }
    else               { W = Wv; bs = bv; scale = 1.0f; }
#pragma unroll
    for (int rep = 0; rep < 4; ++rep) {
      int idx = tid + rep * 256, r = idx >> 4, c4 = idx & 15;
      float4 v = *reinterpret_cast<const float4*>(W + (size_t)(kt * 64 + r) * 64 + c4 * 4);
      Ls[r][c4 * 4 + 0] = v.x; Ls[r][c4 * 4 + 1] = v.y;
      Ls[r][c4 * 4 + 2] = v.z; Ls[r][c4 * 4 + 3] = v.w;
    }
    __syncthreads();
    const int n = tid >> 2, ch = tid & 3;
    __align__(16) unsigned short tmp[16];
#pragma unroll
    for (int j = 0; j < 16; ++j) tmp[j] = f2bf(Ls[ch * 16 + j][n] * scale);
    unsigned short* dst = Wt + (size_t)(mat * 64 + n) * INS + kt * 64 + ch * 16;
    *reinterpret_cast<int4*>(dst)     = *reinterpret_cast<const int4*>(tmp);
    *reinterpret_cast<int4*>(dst + 8) = *reinterpret_cast<const int4*>(tmp + 8);
    if (kt == 0 && tid < 64) bc[mat * 64 + tid] = bs[tid] * scale;
  }
  gbar(flags0, blk, tid);

  // ---------------- phase 1: QKV projection (16 rows/block) ------------------
  {
    const int row0 = blk * 16;
    const float* Xr = X + (size_t)(row0 + l16) * INS + quad * 8;
    const unsigned short* Wb = Wt + (size_t)(wave * 48 + l16) * INS + quad * 8;

    f32x4 acc[3];
#pragma unroll
    for (int i = 0; i < 3; ++i) acc[i] = (f32x4){0.f, 0.f, 0.f, 0.f};

    auto load = [&](int kc, QkvF& f) {
      const int ko = kc * 32;
      f.x0 = *reinterpret_cast<const float4*>(Xr + ko);
      f.x1 = *reinterpret_cast<const float4*>(Xr + ko + 4);
#pragma unroll
      for (int nt = 0; nt < 3; ++nt)
        f.b[nt] = *reinterpret_cast<const short8*>(Wb + (size_t)nt * 16 * INS + ko);
    };
    auto comp = [&](QkvF& f) {
      short8 a = cvt8(f.x0, f.x1);
#pragma unroll
      for (int nt = 0; nt < 3; ++nt)
        acc[nt] = __builtin_amdgcn_mfma_f32_16x16x32_bf16(a, f.b[nt], acc[nt], 0, 0, 0);
    };

    QkvF fa, fb;
    load(0, fa);
    for (int kc = 0; kc < 24; kc += 2) {
      load(kc + 1, fb);
      comp(fa);
      if (kc + 2 < 24) load(kc + 2, fa);
      comp(fb);
    }

    const int gm0 = row0 + quad * 4;
#pragma unroll
    for (int nt = 0; nt < 3; ++nt) {
      const int n = wave * 48 + nt * 16 + l16;
      const float bias = bc[n];
      if (n < 128) {
        unsigned short* dstbase = (n < 64) ? Qg : Kg;
        const int nn = n & 63;
#pragma unroll
        for (int r = 0; r < 4; ++r)
          dstbase[(size_t)(gm0 + r) * OUTS + nn] = f2bf(acc[nt][r] + bias);
      } else {
        const int d = n - 128;
        const int batch = gm0 >> 11, s0 = gm0 & 2047;
        ushort4 pk;
        pk.x = f2bf(acc[nt][0] + bias);
        pk.y = f2bf(acc[nt][1] + bias);
        pk.z = f2bf(acc[nt][2] + bias);
        pk.w = f2bf(acc[nt][3] + bias);
        *reinterpret_cast<ushort4*>(&Vtg[((size_t)batch * OUTS + d) * SS + s0]) = pk;
      }
    }
  }
  gbar(flags1, blk, tid);

  // ---------------- phase 2: attention, key-split across the 4 waves ---------
  {
    float* Obuf = reinterpret_cast<float*>(smem);            // [4][16][64]
    float* Lbuf = reinterpret_cast<float*>(smem + 16384);    // [4][16]
    unsigned short* Ps = reinterpret_cast<unsigned short*>(smem + 16640);
    const int bt = blk >> 7;
    const int q0 = (blk & 127) * 16;
    const unsigned short* Qb = Qg + (size_t)bt * SS * OUTS;
    const unsigned short* Kb = Kg + (size_t)bt * SS * OUTS;
    const unsigned short* Vb = Vtg + (size_t)bt * OUTS * SS;
    const int jbeg = wave * 512;
    unsigned short* Pw = Ps + wave * 16 * LDP;

    short8 aq[2];
#pragma unroll
    for (int ks = 0; ks < 2; ++ks)
      aq[ks] = *reinterpret_cast<const short8*>(
          Qb + (size_t)(q0 + l16) * OUTS + ks * 32 + quad * 8);

    f32x4 oacc[4];
#pragma unroll
    for (int nt = 0; nt < 4; ++nt) oacc[nt] = (f32x4){0.f, 0.f, 0.f, 0.f};
    float lsum[4] = {0.f, 0.f, 0.f, 0.f};

    auto load = [&](int it, AttF& f) {
      const int j0 = jbeg + it * 32;
#pragma unroll
      for (int nt2 = 0; nt2 < 2; ++nt2)
#pragma unroll
        for (int ks = 0; ks < 2; ++ks)
          f.k[nt2][ks] = *reinterpret_cast<const short8*>(
              Kb + (size_t)(j0 + nt2 * 16 + l16) * OUTS + ks * 32 + quad * 8);
#pragma unroll
      for (int nt = 0; nt < 4; ++nt)
        f.v[nt] = *reinterpret_cast<const short8*>(
            Vb + (size_t)(nt * 16 + l16) * SS + j0 + quad * 8);
    };
    auto comp = [&](AttF& f) {
      f32x4 sc[2];
      sc[0] = (f32x4){0.f,0.f,0.f,0.f}; sc[1] = (f32x4){0.f,0.f,0.f,0.f};
#pragma unroll
      for (int ks = 0; ks < 2; ++ks)
#pragma unroll
        for (int nt2 = 0; nt2 < 2; ++nt2)
          sc[nt2] = __builtin_amdgcn_mfma_f32_16x16x32_bf16(aq[ks], f.k[nt2][ks], sc[nt2], 0, 0, 0);
#pragma unroll
      for (int nt2 = 0; nt2 < 2; ++nt2)
#pragma unroll
        for (int r = 0; r < 4; ++r) {
          float p = __expf(sc[nt2][r]);
          lsum[r] += p;
          Pw[(quad * 4 + r) * LDP + nt2 * 16 + l16] = f2bf(p);
        }
      short8 ap = *reinterpret_cast<const short8*>(&Pw[l16 * LDP + quad * 8]);
#pragma unroll
      for (int nt = 0; nt < 4; ++nt)
        oacc[nt] = __builtin_amdgcn_mfma_f32_16x16x32_bf16(ap, f.v[nt], oacc[nt], 0, 0, 0);
    };

    AttF fa, fb;
    load(0, fa);
    for (int it = 0; it < 16; it += 2) {
      load(it + 1, fb);
      comp(fa);
      if (it + 2 < 16) load(it + 2, fa);
      comp(fb);
    }

    // per-wave row sums of lsum across the 16 l16 lanes
#pragma unroll
    for (int st = 1; st < 16; st <<= 1)
#pragma unroll
      for (int r = 0; r < 4; ++r) lsum[r] += __shfl_xor(lsum[r], st, 64);

    // stash per-wave partials in LDS, combine across the 4 key-split waves
#pragma unroll
    for (int nt = 0; nt < 4; ++nt)
#pragma unroll
      for (int r = 0; r < 4; ++r)
        Obuf[(wave * 16 + quad * 4 + r) * 64 + nt * 16 + l16] = oacc[nt][r];
    if (l16 == 0) {
#pragma unroll
      for (int r = 0; r < 4; ++r) Lbuf[wave * 16 + quad * 4 + r] = lsum[r];
    }
    __syncthreads();

    const int row = tid >> 4, c = (tid & 15) * 4;
    float4 s = make_float4(0.f, 0.f, 0.f, 0.f);
    float l = 0.f;
#pragma unroll
    for (int w = 0; w < 4; ++w) {
      float4 t = *reinterpret_cast<const float4*>(&Obuf[((w * 16 + row) * 64) + c]);
      s.x += t.x; s.y += t.y; s.z += t.z; s.w += t.w;
      l += Lbuf[w * 16 + row];
    }
    const float inv = 1.0f / l;
    *reinterpret_cast<float4*>(&out[((size_t)(bt * SS + q0 + row)) * OUTS + c]) =
        make_float4(s.x * inv, s.y * inv, s.z * inv, s.w * inv);
  }
}

extern "C" void kernel_launch(void* const* d_in, const int* in_sizes, int n_in,
                              void* d_out, int out_size, void* d_ws, size_t ws_size,
                              hipStream_t stream) {
  const float* X  = (const float*)d_in[0];
  const float* Wq = (const float*)d_in[1];
  const float* bq = (const float*)d_in[2];
  const float* Wk = (const float*)d_in[3];
  const float* bk = (const float*)d_in[4];
  const float* Wv = (const float*)d_in[5];
  const float* bv = (const float*)d_in[6];
  float* out = (float*)d_out;

  char* ws = (char*)d_ws;
  unsigned short* Wt  = (unsigned short*)(ws);                         // 288 KB
  float*          bc  = (float*)(ws + 294912);                         // 768 B
  uint32_t*    flags0 = (uint32_t*)(ws + 320 * 1024);                  // 4 KB
  uint32_t*    flags1 = (uint32_t*)(ws + 325 * 1024);                  // 4 KB
  unsigned short* Qg  = (unsigned short*)(ws + (size_t)1 * 1024 * 1024); // 2 MB
  unsigned short* Kg  = (unsigned short*)(ws + (size_t)3 * 1024 * 1024); // 2 MB
  unsigned short* Vtg = (unsigned short*)(ws + (size_t)5 * 1024 * 1024); // 2 MB

  fused<<<GRID, 256, 0, stream>>>(X, Wq, bq, Wk, bk, Wv, bv,
                                  Wt, bc, Qg, Kg, Vtg, flags0, flags1, out);
}

// Round 8
// 173.547 us; speedup vs baseline: 4.7910x; 4.7910x over previous
//
#include <hip/hip_runtime.h>
#include <stdint.h>

#define INS 768
#define OUTS 64
#define BB 8
#define SS 2048
#define LDP 40

typedef __attribute__((ext_vector_type(8))) short short8;
typedef __attribute__((ext_vector_type(4))) float f32x4;

__device__ inline unsigned short f2bf(float f) {
  union { float f; uint32_t u; } v; v.f = f;
  uint32_t r = v.u + 0x7FFFu + ((v.u >> 16) & 1u);  // RNE
  return (unsigned short)(r >> 16);
}

__device__ inline short8 cvt8(float4 a, float4 b) {
  short8 r;
  r[0] = (short)f2bf(a.x); r[1] = (short)f2bf(a.y);
  r[2] = (short)f2bf(a.z); r[3] = (short)f2bf(a.w);
  r[4] = (short)f2bf(b.x); r[5] = (short)f2bf(b.y);
  r[6] = (short)f2bf(b.z); r[7] = (short)f2bf(b.w);
  return r;
}

// ---------------- kernel 1: QKV projection, on-the-fly fp32->bf16 weight cast
// (R6 verbatim — proven correct by identical-absmax deduction R6==R7.)
__global__ __launch_bounds__(256) void qkv(
    const float* __restrict__ X,
    const float* __restrict__ Wq, const float* __restrict__ bq,
    const float* __restrict__ Wk, const float* __restrict__ bk,
    const float* __restrict__ Wv, const float* __restrict__ bv,
    unsigned short* __restrict__ Qg, unsigned short* __restrict__ Kg,
    unsigned short* __restrict__ Vtg) {
  const int tid  = threadIdx.x;
  const int wave = tid >> 6, lane = tid & 63;
  const int quad = lane >> 4, l16 = lane & 15;
  const int row0 = blockIdx.x * 16;
  const float* Xr = X + (size_t)(row0 + l16) * INS + quad * 8;

  const float* Wm[3]; const float* Bm[3]; float scl[3]; int col0[3];
#pragma unroll
  for (int nt = 0; nt < 3; ++nt) {
    const int n0 = wave * 48 + nt * 16;
    const int mat = n0 >> 6;
    col0[nt] = n0 & 63;
    if (mat == 0)      { Wm[nt] = Wq; Bm[nt] = bq; scl[nt] = 0.125f; }
    else if (mat == 1) { Wm[nt] = Wk; Bm[nt] = bk; scl[nt] = 1.0f; }
    else               { Wm[nt] = Wv; Bm[nt] = bv; scl[nt] = 1.0f; }
  }

  f32x4 acc[3];
#pragma unroll
  for (int i = 0; i < 3; ++i) acc[i] = (f32x4){0.f, 0.f, 0.f, 0.f};

#pragma unroll 2
  for (int kc = 0; kc < 24; ++kc) {
    const int ko = kc * 32;
    float4 x0 = *reinterpret_cast<const float4*>(Xr + ko);
    float4 x1 = *reinterpret_cast<const float4*>(Xr + ko + 4);
    float wf[3][8];
#pragma unroll
    for (int nt = 0; nt < 3; ++nt) {
      const float* src = Wm[nt] + (size_t)(ko + quad * 8) * OUTS + col0[nt] + l16;
#pragma unroll
      for (int j = 0; j < 8; ++j) wf[nt][j] = src[(size_t)j * OUTS];
    }
    short8 a = cvt8(x0, x1);
#pragma unroll
    for (int nt = 0; nt < 3; ++nt) {
      short8 b;
#pragma unroll
      for (int j = 0; j < 8; ++j) b[j] = (short)f2bf(wf[nt][j] * scl[nt]);
      acc[nt] = __builtin_amdgcn_mfma_f32_16x16x32_bf16(a, b, acc[nt], 0, 0, 0);
    }
  }

  const int gm0 = row0 + quad * 4;
#pragma unroll
  for (int nt = 0; nt < 3; ++nt) {
    const int n = wave * 48 + nt * 16 + l16;
    const float bias = Bm[nt][col0[nt] + l16] * scl[nt];
    if (n < 128) {
      unsigned short* dstbase = (n < 64) ? Qg : Kg;
      const int nn = n & 63;
#pragma unroll
      for (int r = 0; r < 4; ++r)
        dstbase[(size_t)(gm0 + r) * OUTS + nn] = f2bf(acc[nt][r] + bias);
    } else {
      const int d = n - 128;
      const int batch = gm0 >> 11, s0 = gm0 & 2047;
      ushort4 pk;
      pk.x = f2bf(acc[nt][0] + bias);
      pk.y = f2bf(acc[nt][1] + bias);
      pk.z = f2bf(acc[nt][2] + bias);
      pk.w = f2bf(acc[nt][3] + bias);
      *reinterpret_cast<ushort4*>(&Vtg[((size_t)batch * OUTS + d) * SS + s0]) = pk;
    }
  }
}

// ---------------- kernel 2: attention (R3 VERBATIM — proven pass) ------------
struct AttF { short8 k[2][2]; short8 v[4]; };

__global__ __launch_bounds__(256) void attn(
    const unsigned short* __restrict__ Qg, const unsigned short* __restrict__ Kg,
    const unsigned short* __restrict__ Vtg,
    float* __restrict__ OP, float* __restrict__ LS) {
  __shared__ __align__(16) unsigned short Ps[4][2][16 * LDP];
  const int tid  = threadIdx.x;
  const int wave = tid >> 6, lane = tid & 63;
  const int quad = lane >> 4, l16 = lane & 15;
  const int bt  = blockIdx.x >> 6;
  const int rem = blockIdx.x & 63;
  const int qb  = rem >> 2, ksl = rem & 3;
  const int q0 = qb * 128 + wave * 32;
  const unsigned short* Qb = Qg + (size_t)bt * SS * OUTS;
  const unsigned short* Kb = Kg + (size_t)bt * SS * OUTS;
  const unsigned short* Vb = Vtg + (size_t)bt * OUTS * SS;

  short8 aq[2][2];
#pragma unroll
  for (int mh = 0; mh < 2; ++mh)
#pragma unroll
    for (int ks = 0; ks < 2; ++ks)
      aq[mh][ks] = *reinterpret_cast<const short8*>(
          Qb + (size_t)(q0 + mh * 16 + l16) * OUTS + ks * 32 + quad * 8);

  f32x4 oacc[2][4];
#pragma unroll
  for (int mh = 0; mh < 2; ++mh)
#pragma unroll
    for (int nt = 0; nt < 4; ++nt) oacc[mh][nt] = (f32x4){0.f, 0.f, 0.f, 0.f};
  float lsum[2][4] = {{0.f,0.f,0.f,0.f},{0.f,0.f,0.f,0.f}};

  const int jbeg = ksl * 512;
  for (int j0 = jbeg; j0 < jbeg + 512; j0 += 32) {
    short8 bk[2][2], bv[4];
#pragma unroll
    for (int nt2 = 0; nt2 < 2; ++nt2)
#pragma unroll
      for (int ks = 0; ks < 2; ++ks)
        bk[nt2][ks] = *reinterpret_cast<const short8*>(
            Kb + (size_t)(j0 + nt2 * 16 + l16) * OUTS + ks * 32 + quad * 8);
#pragma unroll
    for (int nt = 0; nt < 4; ++nt)
      bv[nt] = *reinterpret_cast<const short8*>(
          Vb + (size_t)(nt * 16 + l16) * SS + j0 + quad * 8);

#pragma unroll
    for (int mh = 0; mh < 2; ++mh) {
      f32x4 sc[2];
      sc[0] = (f32x4){0.f,0.f,0.f,0.f}; sc[1] = (f32x4){0.f,0.f,0.f,0.f};
#pragma unroll
      for (int ks = 0; ks < 2; ++ks)
#pragma unroll
        for (int nt2 = 0; nt2 < 2; ++nt2)
          sc[nt2] = __builtin_amdgcn_mfma_f32_16x16x32_bf16(aq[mh][ks], bk[nt2][ks], sc[nt2], 0, 0, 0);

      unsigned short* Pw = Ps[wave][mh];
#pragma unroll
      for (int nt2 = 0; nt2 < 2; ++nt2)
#pragma unroll
        for (int r = 0; r < 4; ++r) {
          float p = __expf(sc[nt2][r]);
          lsum[mh][r] += p;
          Pw[(quad * 4 + r) * LDP + nt2 * 16 + l16] = f2bf(p);
        }
      short8 ap = *reinterpret_cast<const short8*>(&Pw[l16 * LDP + quad * 8]);
#pragma unroll
      for (int nt = 0; nt < 4; ++nt)
        oacc[mh][nt] = __builtin_amdgcn_mfma_f32_16x16x32_bf16(ap, bv[nt], oacc[mh][nt], 0, 0, 0);
    }
  }

#pragma unroll
  for (int st = 1; st < 16; st <<= 1)
#pragma unroll
    for (int mh = 0; mh < 2; ++mh)
#pragma unroll
      for (int r = 0; r < 4; ++r) lsum[mh][r] += __shfl_xor(lsum[mh][r], st, 64);

  float* OPb = OP + ((size_t)ksl * BB + bt) * SS * OUTS;
#pragma unroll
  for (int mh = 0; mh < 2; ++mh)
#pragma unroll
    for (int nt = 0; nt < 4; ++nt)
#pragma unroll
      for (int r = 0; r < 4; ++r) {
        int q = q0 + mh * 16 + quad * 4 + r;
        OPb[(size_t)q * OUTS + nt * 16 + l16] = oacc[mh][nt][r];
      }
  if (l16 == 0) {
#pragma unroll
    for (int mh = 0; mh < 2; ++mh)
#pragma unroll
      for (int r = 0; r < 4; ++r)
        LS[(size_t)ksl * BB * SS + bt * SS + q0 + mh * 16 + quad * 4 + r] = lsum[mh][r];
  }
}

// ---------------- kernel 3: combine key-split partials (R3 VERBATIM) ---------
__global__ __launch_bounds__(256) void combine(
    const float* __restrict__ OP, const float* __restrict__ LS,
    float* __restrict__ out) {
  const size_t i4 = (size_t)blockIdx.x * 256 + threadIdx.x;  // float4 index
  const size_t row = (i4 * 4) >> 6;                          // bt*S + q
  float4 o = make_float4(0.f, 0.f, 0.f, 0.f);
  float l = 0.f;
#pragma unroll
  for (int ks = 0; ks < 4; ++ks) {
    float4 t = reinterpret_cast<const float4*>(OP + (size_t)ks * BB * SS * OUTS)[i4];
    o.x += t.x; o.y += t.y; o.z += t.z; o.w += t.w;
    l += LS[(size_t)ks * BB * SS + row];
  }
  const float inv = 1.0f / l;
  reinterpret_cast<float4*>(out)[i4] = make_float4(o.x * inv, o.y * inv, o.z * inv, o.w * inv);
}

extern "C" void kernel_launch(void* const* d_in, const int* in_sizes, int n_in,
                              void* d_out, int out_size, void* d_ws, size_t ws_size,
                              hipStream_t stream) {
  const float* X  = (const float*)d_in[0];
  const float* Wq = (const float*)d_in[1];
  const float* bq = (const float*)d_in[2];
  const float* Wk = (const float*)d_in[3];
  const float* bk = (const float*)d_in[4];
  const float* Wv = (const float*)d_in[5];
  const float* bv = (const float*)d_in[6];
  float* out = (float*)d_out;

  char* ws = (char*)d_ws;
  unsigned short* Qg  = (unsigned short*)(ws);                              // 2 MB
  unsigned short* Kg  = (unsigned short*)(ws + (size_t)2 * 1024 * 1024);    // 2 MB
  unsigned short* Vtg = (unsigned short*)(ws + (size_t)4 * 1024 * 1024);    // 2 MB
  float*          OP  = (float*)(ws + (size_t)7 * 1024 * 1024);             // 16 MB
  float*          LS  = (float*)(ws + (size_t)23 * 1024 * 1024);            // 256 KB

  qkv<<<1024, 256, 0, stream>>>(X, Wq, bq, Wk, bk, Wv, bv, Qg, Kg, Vtg);
  attn<<<512, 256, 0, stream>>>(Qg, Kg, Vtg, OP, LS);
  combine<<<1024, 256, 0, stream>>>(OP, LS, out);
}

// Round 9
// 171.127 us; speedup vs baseline: 4.8587x; 1.0141x over previous
//
#include <hip/hip_runtime.h>
#include <hip/hip_bf16.h>
#include <stdint.h>

#define INS 768
#define OUTS 64
#define BB 8
#define SS 2048
#define LDP 40

typedef __attribute__((ext_vector_type(8))) short short8;
typedef __attribute__((ext_vector_type(4))) float f32x4;

__device__ inline unsigned short f2bf(float f) {
  union { float f; uint32_t u; } v; v.f = f;
  uint32_t r = v.u + 0x7FFFu + ((v.u >> 16) & 1u);  // RNE
  return (unsigned short)(r >> 16);
}

// hardware packed f32->bf16 (v_cvt_pk_bf16_f32), RNE — same rounding as f2bf
__device__ inline short8 cvt8hw(float4 a, float4 b) {
  union { __hip_bfloat162 h[4]; short8 s; } u;
  u.h[0] = __float22bfloat162_rn(make_float2(a.x, a.y));
  u.h[1] = __float22bfloat162_rn(make_float2(a.z, a.w));
  u.h[2] = __float22bfloat162_rn(make_float2(b.x, b.y));
  u.h[3] = __float22bfloat162_rn(make_float2(b.z, b.w));
  return u.s;
}
__device__ inline short8 cvt8w(const float* wf, float scl) {
  union { __hip_bfloat162 h[4]; short8 s; } u;
#pragma unroll
  for (int j = 0; j < 4; ++j)
    u.h[j] = __float22bfloat162_rn(make_float2(wf[2 * j] * scl, wf[2 * j + 1] * scl));
  return u.s;
}

// ---------------- kernel 1: QKV projection, in-block 2-way K-split -----------
// block = 512 threads = 8 waves: chg = wave&3 (channel group of 48), kh =
// wave>>2 (K-half of 384). grid 1024 -> 4 blocks/CU, 32 waves/CU demand.
// Per-wave chain: 12 iterations (was 24). K-half partials combined via LDS,
// K-half-0 wave runs the R6-proven epilogue verbatim.
__global__ __launch_bounds__(512) void qkv(
    const float* __restrict__ X,
    const float* __restrict__ Wq, const float* __restrict__ bq,
    const float* __restrict__ Wk, const float* __restrict__ bk,
    const float* __restrict__ Wv, const float* __restrict__ bv,
    unsigned short* __restrict__ Qg, unsigned short* __restrict__ Kg,
    unsigned short* __restrict__ Vtg) {
  __shared__ float Cbuf[4][64][13];   // +1 pad: 13 coprime w/ 32 banks -> conflict-free
  const int tid  = threadIdx.x;
  const int wave = tid >> 6, lane = tid & 63;
  const int chg  = wave & 3, kh = wave >> 2;
  const int quad = lane >> 4, l16 = lane & 15;
  const int row0 = blockIdx.x * 16;
  const float* Xr = X + (size_t)(row0 + l16) * INS + kh * 384 + quad * 8;

  const float* Wm[3]; const float* Bm[3]; float scl[3]; int col0[3];
#pragma unroll
  for (int nt = 0; nt < 3; ++nt) {
    const int n0 = chg * 48 + nt * 16;
    const int mat = n0 >> 6;
    col0[nt] = n0 & 63;
    if (mat == 0)      { Wm[nt] = Wq; Bm[nt] = bq; scl[nt] = 0.125f; }
    else if (mat == 1) { Wm[nt] = Wk; Bm[nt] = bk; scl[nt] = 1.0f; }
    else               { Wm[nt] = Wv; Bm[nt] = bv; scl[nt] = 1.0f; }
  }

  f32x4 acc[3];
#pragma unroll
  for (int i = 0; i < 3; ++i) acc[i] = (f32x4){0.f, 0.f, 0.f, 0.f};

#pragma unroll 2
  for (int kc = 0; kc < 12; ++kc) {
    const int ko = kc * 32;                       // within this K-half
    const int kk = kh * 384 + ko;                 // absolute K offset
    float4 x0 = *reinterpret_cast<const float4*>(Xr + ko);
    float4 x1 = *reinterpret_cast<const float4*>(Xr + ko + 4);
    float wf[3][8];
#pragma unroll
    for (int nt = 0; nt < 3; ++nt) {
      const float* src = Wm[nt] + (size_t)(kk + quad * 8) * OUTS + col0[nt] + l16;
#pragma unroll
      for (int j = 0; j < 8; ++j) wf[nt][j] = src[(size_t)j * OUTS];
    }
    short8 a = cvt8hw(x0, x1);
#pragma unroll
    for (int nt = 0; nt < 3; ++nt) {
      short8 b = cvt8w(wf[nt], scl[nt]);
      acc[nt] = __builtin_amdgcn_mfma_f32_16x16x32_bf16(a, b, acc[nt], 0, 0, 0);
    }
  }

  // combine K-half partials through LDS
  if (kh == 1) {
#pragma unroll
    for (int nt = 0; nt < 3; ++nt)
#pragma unroll
      for (int r = 0; r < 4; ++r) Cbuf[chg][lane][nt * 4 + r] = acc[nt][r];
  }
  __syncthreads();
  if (kh == 0) {
#pragma unroll
    for (int nt = 0; nt < 3; ++nt)
#pragma unroll
      for (int r = 0; r < 4; ++r) acc[nt][r] += Cbuf[chg][lane][nt * 4 + r];

    // epilogue (R6-proven, wave->chg): Q,K row-major bf16; V transposed
    const int gm0 = row0 + quad * 4;
#pragma unroll
    for (int nt = 0; nt < 3; ++nt) {
      const int n = chg * 48 + nt * 16 + l16;
      const float bias = Bm[nt][col0[nt] + l16] * scl[nt];
      if (n < 128) {
        unsigned short* dstbase = (n < 64) ? Qg : Kg;
        const int nn = n & 63;
#pragma unroll
        for (int r = 0; r < 4; ++r)
          dstbase[(size_t)(gm0 + r) * OUTS + nn] = f2bf(acc[nt][r] + bias);
      } else {
        const int d = n - 128;
        const int batch = gm0 >> 11, s0 = gm0 & 2047;
        ushort4 pk;
        pk.x = f2bf(acc[nt][0] + bias);
        pk.y = f2bf(acc[nt][1] + bias);
        pk.z = f2bf(acc[nt][2] + bias);
        pk.w = f2bf(acc[nt][3] + bias);
        *reinterpret_cast<ushort4*>(&Vtg[((size_t)batch * OUTS + d) * SS + s0]) = pk;
      }
    }
  }
}

// ---------------- kernel 2: attention (R3/R8 VERBATIM — proven pass) ---------
__global__ __launch_bounds__(256) void attn(
    const unsigned short* __restrict__ Qg, const unsigned short* __restrict__ Kg,
    const unsigned short* __restrict__ Vtg,
    float* __restrict__ OP, float* __restrict__ LS) {
  __shared__ __align__(16) unsigned short Ps[4][2][16 * LDP];
  const int tid  = threadIdx.x;
  const int wave = tid >> 6, lane = tid & 63;
  const int quad = lane >> 4, l16 = lane & 15;
  const int bt  = blockIdx.x >> 6;
  const int rem = blockIdx.x & 63;
  const int qb  = rem >> 2, ksl = rem & 3;
  const int q0 = qb * 128 + wave * 32;
  const unsigned short* Qb = Qg + (size_t)bt * SS * OUTS;
  const unsigned short* Kb = Kg + (size_t)bt * SS * OUTS;
  const unsigned short* Vb = Vtg + (size_t)bt * OUTS * SS;

  short8 aq[2][2];
#pragma unroll
  for (int mh = 0; mh < 2; ++mh)
#pragma unroll
    for (int ks = 0; ks < 2; ++ks)
      aq[mh][ks] = *reinterpret_cast<const short8*>(
          Qb + (size_t)(q0 + mh * 16 + l16) * OUTS + ks * 32 + quad * 8);

  f32x4 oacc[2][4];
#pragma unroll
  for (int mh = 0; mh < 2; ++mh)
#pragma unroll
    for (int nt = 0; nt < 4; ++nt) oacc[mh][nt] = (f32x4){0.f, 0.f, 0.f, 0.f};
  float lsum[2][4] = {{0.f,0.f,0.f,0.f},{0.f,0.f,0.f,0.f}};

  const int jbeg = ksl * 512;
  for (int j0 = jbeg; j0 < jbeg + 512; j0 += 32) {
    short8 bk[2][2], bv[4];
#pragma unroll
    for (int nt2 = 0; nt2 < 2; ++nt2)
#pragma unroll
      for (int ks = 0; ks < 2; ++ks)
        bk[nt2][ks] = *reinterpret_cast<const short8*>(
            Kb + (size_t)(j0 + nt2 * 16 + l16) * OUTS + ks * 32 + quad * 8);
#pragma unroll
    for (int nt = 0; nt < 4; ++nt)
      bv[nt] = *reinterpret_cast<const short8*>(
          Vb + (size_t)(nt * 16 + l16) * SS + j0 + quad * 8);

#pragma unroll
    for (int mh = 0; mh < 2; ++mh) {
      f32x4 sc[2];
      sc[0] = (f32x4){0.f,0.f,0.f,0.f}; sc[1] = (f32x4){0.f,0.f,0.f,0.f};
#pragma unroll
      for (int ks = 0; ks < 2; ++ks)
#pragma unroll
        for (int nt2 = 0; nt2 < 2; ++nt2)
          sc[nt2] = __builtin_amdgcn_mfma_f32_16x16x32_bf16(aq[mh][ks], bk[nt2][ks], sc[nt2], 0, 0, 0);

      unsigned short* Pw = Ps[wave][mh];
#pragma unroll
      for (int nt2 = 0; nt2 < 2; ++nt2)
#pragma unroll
        for (int r = 0; r < 4; ++r) {
          float p = __expf(sc[nt2][r]);
          lsum[mh][r] += p;
          Pw[(quad * 4 + r) * LDP + nt2 * 16 + l16] = f2bf(p);
        }
      short8 ap = *reinterpret_cast<const short8*>(&Pw[l16 * LDP + quad * 8]);
#pragma unroll
      for (int nt = 0; nt < 4; ++nt)
        oacc[mh][nt] = __builtin_amdgcn_mfma_f32_16x16x32_bf16(ap, bv[nt], oacc[mh][nt], 0, 0, 0);
    }
  }

#pragma unroll
  for (int st = 1; st < 16; st <<= 1)
#pragma unroll
    for (int mh = 0; mh < 2; ++mh)
#pragma unroll
      for (int r = 0; r < 4; ++r) lsum[mh][r] += __shfl_xor(lsum[mh][r], st, 64);

  float* OPb = OP + ((size_t)ksl * BB + bt) * SS * OUTS;
#pragma unroll
  for (int mh = 0; mh < 2; ++mh)
#pragma unroll
    for (int nt = 0; nt < 4; ++nt)
#pragma unroll
      for (int r = 0; r < 4; ++r) {
        int q = q0 + mh * 16 + quad * 4 + r;
        OPb[(size_t)q * OUTS + nt * 16 + l16] = oacc[mh][nt][r];
      }
  if (l16 == 0) {
#pragma unroll
    for (int mh = 0; mh < 2; ++mh)
#pragma unroll
      for (int r = 0; r < 4; ++r)
        LS[(size_t)ksl * BB * SS + bt * SS + q0 + mh * 16 + quad * 4 + r] = lsum[mh][r];
  }
}

// ---------------- kernel 3: combine key-split partials (R3/R8 VERBATIM) ------
__global__ __launch_bounds__(256) void combine(
    const float* __restrict__ OP, const float* __restrict__ LS,
    float* __restrict__ out) {
  const size_t i4 = (size_t)blockIdx.x * 256 + threadIdx.x;  // float4 index
  const size_t row = (i4 * 4) >> 6;                          // bt*S + q
  float4 o = make_float4(0.f, 0.f, 0.f, 0.f);
  float l = 0.f;
#pragma unroll
  for (int ks = 0; ks < 4; ++ks) {
    float4 t = reinterpret_cast<const float4*>(OP + (size_t)ks * BB * SS * OUTS)[i4];
    o.x += t.x; o.y += t.y; o.z += t.z; o.w += t.w;
    l += LS[(size_t)ks * BB * SS + row];
  }
  const float inv = 1.0f / l;
  reinterpret_cast<float4*>(out)[i4] = make_float4(o.x * inv, o.y * inv, o.z * inv, o.w * inv);
}

extern "C" void kernel_launch(void* const* d_in, const int* in_sizes, int n_in,
                              void* d_out, int out_size, void* d_ws, size_t ws_size,
                              hipStream_t stream) {
  const float* X  = (const float*)d_in[0];
  const float* Wq = (const float*)d_in[1];
  const float* bq = (const float*)d_in[2];
  const float* Wk = (const float*)d_in[3];
  const float* bk = (const float*)d_in[4];
  const float* Wv = (const float*)d_in[5];
  const float* bv = (const float*)d_in[6];
  float* out = (float*)d_out;

  char* ws = (char*)d_ws;
  unsigned short* Qg  = (unsigned short*)(ws);                              // 2 MB
  unsigned short* Kg  = (unsigned short*)(ws + (size_t)2 * 1024 * 1024);    // 2 MB
  unsigned short* Vtg = (unsigned short*)(ws + (size_t)4 * 1024 * 1024);    // 2 MB
  float*          OP  = (float*)(ws + (size_t)7 * 1024 * 1024);             // 16 MB
  float*          LS  = (float*)(ws + (size_t)23 * 1024 * 1024);            // 256 KB

  qkv<<<1024, 512, 0, stream>>>(X, Wq, bq, Wk, bk, Wv, bv, Qg, Kg, Vtg);
  attn<<<512, 256, 0, stream>>>(Qg, Kg, Vtg, OP, LS);
  combine<<<1024, 256, 0, stream>>>(OP, LS, out);
}